// Round 11
// baseline (465.665 us; speedup 1.0000x reference)
//
#include <hip/hip_runtime.h>

#define N_NODES 100000
#define N_EDGES 1600000
#define F_NODE  32
#define F_GLOB  16
#define HDIM    64
#define OUTDIM  64
#define PBLK    512     // partition blocks
#define CHUNK   3125    // edges per partition block (512*3125 = 1.6M exactly)
#define EPT     13      // ceil(CHUNK/256)
#define NSH     128     // dst shards
#define SHN     782     // nodes per shard (ceil(100000/128))
#define SCAP    13568   // per-shard stage capacity (mean 12500, +9 sigma)
#define NTILE   (N_NODES / 16)   // 6250 MFMA row-tiles
#define MFB     512     // persistent MFMA blocks
#define NPB     3125    // pull blocks (32 nodes each)

typedef unsigned short u16;
typedef unsigned int   u32;
typedef __attribute__((ext_vector_type(8))) short short8v;  // 8 bf16 (4 VGPR)
typedef __attribute__((ext_vector_type(4))) float f32x4;    // MFMA acc

__device__ __forceinline__ u16 f2b(float f) {            // fp32 -> bf16 RNE
    u32 u = __float_as_uint(f);
    return (u16)((u + 0x7fffu + ((u >> 16) & 1u)) >> 16);
}
__device__ __forceinline__ float blo(u32 p) { return __uint_as_float(p << 16); }
__device__ __forceinline__ float bhi(u32 p) { return __uint_as_float(p & 0xffff0000u); }

// ---------- CSR build: partition -> per-shard LDS counting sort ----------

__global__ void __launch_bounds__(256)
k_part(const int* __restrict__ src, const int* __restrict__ dst,
       int* __restrict__ shcnt, int2* __restrict__ stage) {
    __shared__ int lcnt[NSH];
    __shared__ int gbase[NSH];
    int t = threadIdx.x;
    for (int i = t; i < NSH; i += 256) lcnt[i] = 0;
    __syncthreads();
    int e0 = blockIdx.x * CHUNK;
    int n = N_EDGES - e0; if (n > CHUNK) n = CHUNK; if (n < 0) n = 0;
    int2 ev[EPT]; int rk[EPT]; int sh[EPT];
    #pragma unroll
    for (int j = 0; j < EPT; ++j) {
        int i = t + j * 256;
        if (i < n) {
            int sv = __builtin_nontemporal_load(&src[e0 + i]);
            int dv = __builtin_nontemporal_load(&dst[e0 + i]);
            int k = dv / SHN;
            ev[j] = make_int2(sv, dv);
            sh[j] = k;
            rk[j] = atomicAdd(&lcnt[k], 1);
        }
    }
    __syncthreads();
    for (int i = t; i < NSH; i += 256)
        gbase[i] = atomicAdd(&shcnt[i], lcnt[i]);
    __syncthreads();
    #pragma unroll
    for (int j = 0; j < EPT; ++j) {
        int i = t + j * 256;
        if (i < n) {
            int p = gbase[sh[j]] + rk[j];
            if (p < SCAP) stage[(size_t)sh[j] * SCAP + p] = ev[j];
        }
    }
}

// also emits deg[v] and a 64-bucket global degree histogram (for pull scheduling)
__global__ void __launch_bounds__(1024)
k_build(const int2* __restrict__ stage, const int* __restrict__ shcnt,
        int* __restrict__ rowptr, float* __restrict__ dis, int* __restrict__ col,
        int* __restrict__ deg, int* __restrict__ gbins) {
    __shared__ int shc[NSH];
    __shared__ int hist[1024];
    __shared__ int A[1024];
    __shared__ int B[1024];
    __shared__ int dbin[64];
    int t = threadIdx.x;
    int s = blockIdx.x;
    if (t < NSH) shc[t] = shcnt[t];
    hist[t] = 0;
    if (t < 64) dbin[t] = 0;
    __syncthreads();
    int sb = 0;
    for (int q = 0; q < s; ++q) sb += shc[q];
    int n = shc[s]; if (n > SCAP) n = SCAP;
    const int2* st = stage + (size_t)s * SCAP;
    int v0 = s * SHN;
    for (int p = t; p < n; p += 1024)
        atomicAdd(&hist[st[p].y - v0], 1);
    __syncthreads();
    A[t] = hist[t];
    __syncthreads();
    int* cur = A; int* nxt = B;
    for (int ofs = 1; ofs < 1024; ofs <<= 1) {
        nxt[t] = cur[t] + (t >= ofs ? cur[t - ofs] : 0);
        __syncthreads();
        int* tmp = cur; cur = nxt; nxt = tmp;
    }
    int v = v0 + t;
    bool valid = (t < SHN && v < N_NODES);
    if (valid) {
        rowptr[v] = sb + cur[t] - hist[t];
        dis[v] = rsqrtf((float)(hist[t] + 1));
        deg[v] = hist[t];
        atomicAdd(&dbin[hist[t] < 63 ? hist[t] : 63], 1);
    }
    if (s == NSH - 1 && t == 0) rowptr[N_NODES] = N_EDGES;
    nxt[t] = sb + cur[t] - hist[t];
    __syncthreads();
    if (t < 64 && dbin[t]) atomicAdd(&gbins[t], dbin[t]);
    for (int p = t; p < n; p += 1024) {
        int2 ed = st[p];
        int slot = atomicAdd(&nxt[ed.y - v0], 1);
        col[slot] = ed.x;
    }
}

// exclusive scan of 64 degree bins -> bucket cursors
__global__ void k_dscan(const int* __restrict__ gbins, int* __restrict__ cursor) {
    __shared__ int a[64];
    int t = threadIdx.x;
    a[t] = gbins[t];
    __syncthreads();
    if (t == 0) { int run = 0; for (int i = 0; i < 64; ++i) { int c = a[i]; a[i] = run; run += c; } }
    __syncthreads();
    cursor[t] = a[t];
}

// scatter nodes into degree-sorted perm (LDS-aggregated bucket reservations)
__global__ void __launch_bounds__(256)
k_dperm(const int* __restrict__ deg, int* __restrict__ cursor, int* __restrict__ perm) {
    __shared__ int lb[64];
    __shared__ int base[64];
    int t = threadIdx.x;
    if (t < 64) lb[t] = 0;
    __syncthreads();
    int bin[4], rk[4];
    #pragma unroll
    for (int j = 0; j < 4; ++j) {
        int v = blockIdx.x * 1024 + j * 256 + t;
        if (v < N_NODES) {
            int d = deg[v]; bin[j] = d < 63 ? d : 63;
            rk[j] = atomicAdd(&lb[bin[j]], 1);
        } else bin[j] = -1;
    }
    __syncthreads();
    if (t < 64) base[t] = atomicAdd(&cursor[t], lb[t]);
    __syncthreads();
    #pragma unroll
    for (int j = 0; j < 4; ++j)
        if (bin[j] >= 0) perm[base[bin[j]] + rk[j]] = blockIdx.x * 1024 + j * 256 + t;
}

// ---------- persistent MFMA dense: out(bf16 Nx64) = op(A(NxK) @ W(f32 Kx64)) ----------
// A-frag: lane l -> row=l&15, k=(l>>4)*8..  B-frag symmetric (built once per wave).
// C/D:    lane l -> col=l&15, row=(l>>4)*4+j   [verified m89 layout]

template<int K, bool BIAS, bool DIS, bool F32A>
__global__ void __launch_bounds__(256)
k_mfma(const void* __restrict__ Aptr, const float* __restrict__ W,
       const float* __restrict__ bias, const float* __restrict__ dis,
       u16* __restrict__ out) {
    constexpr int KB = K / 32;
    int t = threadIdx.x, wid = t >> 6, l = t & 63;
    int lr = l & 15, kc = l >> 4;
    short8v bfrag[4][KB];
    #pragma unroll
    for (int ct = 0; ct < 4; ++ct)
        #pragma unroll
        for (int kb = 0; kb < KB; ++kb)
            #pragma unroll
            for (int j = 0; j < 8; ++j)
                bfrag[ct][kb][j] = (short)f2b(W[(kb * 32 + kc * 8 + j) * HDIM + ct * 16 + lr]);
    float bb[4];
    #pragma unroll
    for (int ct = 0; ct < 4; ++ct) bb[ct] = BIAS ? bias[ct * 16 + lr] : 0.f;
    int gw = blockIdx.x * 4 + wid;
    const int nw = MFB * 4;
    for (int tile = gw; tile < NTILE; tile += nw) {
        int r0 = tile * 16;
        short8v a[KB];
        if (F32A) {
            const float* arow = (const float*)Aptr + (size_t)(r0 + lr) * K + kc * 8;
            #pragma unroll
            for (int kb = 0; kb < KB; ++kb) {
                float4 f0 = *(const float4*)(arow + kb * 32);
                float4 f1 = *(const float4*)(arow + kb * 32 + 4);
                a[kb][0] = (short)f2b(f0.x); a[kb][1] = (short)f2b(f0.y);
                a[kb][2] = (short)f2b(f0.z); a[kb][3] = (short)f2b(f0.w);
                a[kb][4] = (short)f2b(f1.x); a[kb][5] = (short)f2b(f1.y);
                a[kb][6] = (short)f2b(f1.z); a[kb][7] = (short)f2b(f1.w);
            }
        } else {
            const u16* arow = (const u16*)Aptr + (size_t)(r0 + lr) * K + kc * 8;
            #pragma unroll
            for (int kb = 0; kb < KB; ++kb)
                a[kb] = *(const short8v*)(arow + kb * 32);
        }
        f32x4 acc[4];
        #pragma unroll
        for (int ct = 0; ct < 4; ++ct) acc[ct] = (f32x4){0.f, 0.f, 0.f, 0.f};
        #pragma unroll
        for (int ct = 0; ct < 4; ++ct)
            #pragma unroll
            for (int kb = 0; kb < KB; ++kb)
                acc[ct] = __builtin_amdgcn_mfma_f32_16x16x32_bf16(a[kb], bfrag[ct][kb], acc[ct], 0, 0, 0);
        float dv[4];
        #pragma unroll
        for (int j = 0; j < 4; ++j)
            dv[j] = DIS ? dis[r0 + kc * 4 + j] : 1.f;
        #pragma unroll
        for (int ct = 0; ct < 4; ++ct)
            #pragma unroll
            for (int j = 0; j < 4; ++j) {
                int row = r0 + kc * 4 + j;
                float val = acc[ct][j];
                if (BIAS) val += bb[ct];
                if (DIS)  val *= dv[j];
                out[(size_t)row * HDIM + ct * 16 + lr] = f2b(val);
            }
    }
}

// ---------- pull v4: degree-sorted nodes, 8 nodes/wave, 4-deep pipeline ----------

template<bool MEAN>
__global__ void __launch_bounds__(256)
k_pull(const u16* __restrict__ hw, const int* __restrict__ rowptr,
       const int* __restrict__ col, const float* __restrict__ dis,
       const float* __restrict__ b, const int* __restrict__ perm,
       u16* __restrict__ hout, float* __restrict__ partial) {
    __shared__ float ms[64];
    int t = threadIdx.x, wid = t >> 6, lane = t & 63;
    int g = lane >> 3, sub = lane & 7;
    if (MEAN) { if (t < 64) ms[t] = 0.f; __syncthreads(); }
    int v = perm[blockIdx.x * 32 + wid * 8 + g];   // degree-sorted schedule
    const u16* hws = hw + sub * 8;
    uint4 sv = *(const uint4*)(hws + (size_t)v * HDIM);
    float acc[8];
    acc[0] = blo(sv.x); acc[1] = bhi(sv.x);
    acc[2] = blo(sv.y); acc[3] = bhi(sv.y);
    acc[4] = blo(sv.z); acc[5] = bhi(sv.z);
    acc[6] = blo(sv.w); acc[7] = bhi(sv.w);
    int s0 = rowptr[v], s1 = rowptr[v + 1];
    int i = s0;
    for (; i + 4 <= s1; i += 4) {
        int c0 = col[i], c1 = col[i + 1], c2 = col[i + 2], c3 = col[i + 3];
        uint4 a0 = *(const uint4*)(hws + (size_t)c0 * HDIM);
        uint4 a1 = *(const uint4*)(hws + (size_t)c1 * HDIM);
        uint4 a2 = *(const uint4*)(hws + (size_t)c2 * HDIM);
        uint4 a3 = *(const uint4*)(hws + (size_t)c3 * HDIM);
        acc[0] += blo(a0.x) + blo(a1.x); acc[1] += bhi(a0.x) + bhi(a1.x);
        acc[2] += blo(a0.y) + blo(a1.y); acc[3] += bhi(a0.y) + bhi(a1.y);
        acc[4] += blo(a0.z) + blo(a1.z); acc[5] += bhi(a0.z) + bhi(a1.z);
        acc[6] += blo(a0.w) + blo(a1.w); acc[7] += bhi(a0.w) + bhi(a1.w);
        acc[0] += blo(a2.x) + blo(a3.x); acc[1] += bhi(a2.x) + bhi(a3.x);
        acc[2] += blo(a2.y) + blo(a3.y); acc[3] += bhi(a2.y) + bhi(a3.y);
        acc[4] += blo(a2.z) + blo(a3.z); acc[5] += bhi(a2.z) + bhi(a3.z);
        acc[6] += blo(a2.w) + blo(a3.w); acc[7] += bhi(a2.w) + bhi(a3.w);
    }
    for (; i < s1; ++i) {
        int c0 = col[i];
        uint4 a0 = *(const uint4*)(hws + (size_t)c0 * HDIM);
        acc[0] += blo(a0.x); acc[1] += bhi(a0.x);
        acc[2] += blo(a0.y); acc[3] += bhi(a0.y);
        acc[4] += blo(a0.z); acc[5] += bhi(a0.z);
        acc[6] += blo(a0.w); acc[7] += bhi(a0.w);
    }
    float4 b0 = *(const float4*)&b[sub * 8];
    float4 b1 = *(const float4*)&b[sub * 8 + 4];
    float bb[8] = {b0.x, b0.y, b0.z, b0.w, b1.x, b1.y, b1.z, b1.w};
    float dv = dis[v];
    float o[8];
    u32 r[8];
    #pragma unroll
    for (int k = 0; k < 8; ++k) {
        o[k] = fmaxf(bb[k] + dv * acc[k], 0.f);
        u32 u = __float_as_uint(o[k]);
        r[k] = (u + 0x7fffu + ((u >> 16) & 1u)) >> 16;
    }
    uint4 pk;
    pk.x = r[0] | (r[1] << 16); pk.y = r[2] | (r[3] << 16);
    pk.z = r[4] | (r[5] << 16); pk.w = r[6] | (r[7] << 16);
    *(uint4*)(hout + (size_t)v * HDIM + sub * 8) = pk;
    if (MEAN) {
        #pragma unroll
        for (int k = 0; k < 8; ++k) {   // reduce across the 8 node-groups
            o[k] += __shfl_xor(o[k], 8);
            o[k] += __shfl_xor(o[k], 16);
            o[k] += __shfl_xor(o[k], 32);
        }
        if (g == 0)
            #pragma unroll
            for (int k = 0; k < 8; ++k) atomicAdd(&ms[sub * 8 + k], o[k]);
        __syncthreads();
        if (t < 64) partial[(size_t)blockIdx.x * 64 + t] = ms[t];
    }
}

// ---------- readout ----------

__global__ void __launch_bounds__(256)
k_final(const float* __restrict__ partial,
        const float* __restrict__ gfeat,
        const float* __restrict__ wg, const float* __restrict__ bg,
        const float* __restrict__ w1, const float* __restrict__ b1,
        const float* __restrict__ w2, const float* __restrict__ b2,
        float* __restrict__ out) {
    __shared__ float red[4][HDIM];
    __shared__ float xc[2 * HDIM];
    __shared__ float hid[HDIM];
    int t = threadIdx.x, g = t >> 6, lane = t & 63;
    float s = 0.f;
    for (int p = g; p < NPB; p += 4) s += partial[(size_t)p * 64 + lane];
    red[g][lane] = s;
    __syncthreads();
    if (g == 0) {
        xc[lane] = (red[0][lane] + red[1][lane] + red[2][lane] + red[3][lane])
                   / (float)N_NODES;
    } else if (g == 1) {
        float gacc = bg[lane];
        for (int k = 0; k < F_GLOB; ++k) gacc += gfeat[k] * wg[k * HDIM + lane];
        xc[HDIM + lane] = fmaxf(gacc, 0.f);
    }
    __syncthreads();
    float hacc = 0.f;
    for (int k = g * 32; k < (g + 1) * 32; ++k) hacc += xc[k] * w1[k * HDIM + lane];
    red[g][lane] = hacc;
    __syncthreads();
    if (g == 0)
        hid[lane] = fmaxf(b1[lane] + red[0][lane] + red[1][lane]
                          + red[2][lane] + red[3][lane], 0.f);
    __syncthreads();
    float oacc = 0.f;
    for (int k = g * 16; k < (g + 1) * 16; ++k) oacc += hid[k] * w2[k * OUTDIM + lane];
    red[g][lane] = oacc;
    __syncthreads();
    if (g == 0)
        out[lane] = b2[lane] + red[0][lane] + red[1][lane]
                  + red[2][lane] + red[3][lane];
}

// ---------- launch ----------

extern "C" void kernel_launch(void* const* d_in, const int* in_sizes, int n_in,
                              void* d_out, int out_size, void* d_ws, size_t ws_size,
                              hipStream_t stream) {
    const float* x      = (const float*)d_in[0];
    const int*   eidx   = (const int*)d_in[1];
    const float* gfeat  = (const float*)d_in[2];
    const float* w_node = (const float*)d_in[3];
    const float* b_node = (const float*)d_in[4];
    const float* w_glob = (const float*)d_in[5];
    const float* b_glob = (const float*)d_in[6];
    const float* w_c[3] = {(const float*)d_in[7], (const float*)d_in[9], (const float*)d_in[11]};
    const float* b_c[3] = {(const float*)d_in[8], (const float*)d_in[10], (const float*)d_in[12]};
    const float* w_fc1  = (const float*)d_in[13];
    const float* b_fc1  = (const float*)d_in[14];
    const float* w_fc2  = (const float*)d_in[15];
    const float* b_fc2  = (const float*)d_in[16];
    float* out = (float*)d_out;

    const int* srcp = eidx;
    const int* dstp = eidx + N_EDGES;

    char* ws = (char*)d_ws;
    size_t off = 0;
    auto alloc = [&](size_t bytes) -> void* {
        void* p = ws + off;
        off = (off + bytes + 255) & ~(size_t)255;
        return p;
    };
    int*   rowptr  = (int*)  alloc((size_t)(N_NODES + 1) * 4);
    int*   shcnt   = (int*)  alloc(NSH * 4);
    int*   gbins   = (int*)  alloc(64 * 4);
    int*   cursor  = (int*)  alloc(64 * 4);
    float* dis     = (float*)alloc((size_t)N_NODES * 4);
    int*   deg     = (int*)  alloc((size_t)N_NODES * 4);
    int*   perm    = (int*)  alloc((size_t)N_NODES * 4);
    int*   col     = (int*)  alloc((size_t)N_EDGES * 4);
    int2*  stage   = (int2*) alloc((size_t)NSH * SCAP * 8);
    u16*   hbuf    = (u16*)  alloc((size_t)N_NODES * HDIM * 2);
    u16*   hwbuf   = (u16*)  alloc((size_t)N_NODES * HDIM * 2);
    float* partial = (float*)alloc((size_t)NPB * 64 * 4);

    hipMemsetAsync(shcnt, 0, NSH * 4, stream);
    hipMemsetAsync(gbins, 0, 64 * 4, stream);

    k_part <<<PBLK, 256, 0, stream>>>(srcp, dstp, shcnt, stage);
    k_build<<<NSH, 1024, 0, stream>>>(stage, shcnt, rowptr, dis, col, deg, gbins);
    k_dscan<<<1, 64, 0, stream>>>(gbins, cursor);
    k_dperm<<<98, 256, 0, stream>>>(deg, cursor, perm);

    // e = x @ wn + bn (f32 A, converted inline)
    k_mfma<32, true, false, true><<<MFB, 256, 0, stream>>>(x, w_node, b_node, nullptr, hbuf);
    // hw = dis * (e @ wc0)
    k_mfma<64, false, true, false><<<MFB, 256, 0, stream>>>(hbuf, w_c[0], nullptr, dis, hwbuf);
    k_pull<false><<<NPB, 256, 0, stream>>>(hwbuf, rowptr, col, dis, b_c[0], perm, hbuf, nullptr);
    k_mfma<64, false, true, false><<<MFB, 256, 0, stream>>>(hbuf, w_c[1], nullptr, dis, hwbuf);
    k_pull<false><<<NPB, 256, 0, stream>>>(hwbuf, rowptr, col, dis, b_c[1], perm, hbuf, nullptr);
    k_mfma<64, false, true, false><<<MFB, 256, 0, stream>>>(hbuf, w_c[2], nullptr, dis, hwbuf);
    k_pull<true><<<NPB, 256, 0, stream>>>(hwbuf, rowptr, col, dis, b_c[2], perm, hbuf, partial);

    k_final<<<1, 256, 0, stream>>>(partial, gfeat, w_glob, b_glob,
                                   w_fc1, b_fc1, w_fc2, b_fc2, out);
}

// Round 12
// 291.139 us; speedup vs baseline: 1.5995x; 1.5995x over previous
//
#include <hip/hip_runtime.h>

#define N_NODES 100000
#define N_EDGES 1600000
#define F_NODE  32
#define F_GLOB  16
#define HDIM    64
#define OUTDIM  64
#define PBLK    512     // partition blocks
#define CHUNK   3125    // edges per partition block (512*3125 = 1.6M exactly)
#define EPT     13      // ceil(CHUNK/256)
#define NSH     128     // dst shards
#define SHN     782     // nodes per shard (ceil(100000/128))
#define SCAP    13568   // per-shard stage capacity (mean 12500, +9 sigma)
#define NTILE   (N_NODES / 16)   // 6250 MFMA row-tiles
#define MFB     512     // persistent MFMA blocks
#define NPB     3125    // pull blocks (32 nodes each)
#define RB      64      // reduction blocks
#define RROWS   ((NPB + RB - 1) / RB)   // 49 rows per reduction block

typedef unsigned short u16;
typedef unsigned int   u32;
typedef __attribute__((ext_vector_type(8))) short short8v;  // 8 bf16 (4 VGPR)
typedef __attribute__((ext_vector_type(4))) float f32x4;    // MFMA acc

__device__ __forceinline__ u16 f2b(float f) {            // fp32 -> bf16 RNE
    u32 u = __float_as_uint(f);
    return (u16)((u + 0x7fffu + ((u >> 16) & 1u)) >> 16);
}
__device__ __forceinline__ float blo(u32 p) { return __uint_as_float(p << 16); }
__device__ __forceinline__ float bhi(u32 p) { return __uint_as_float(p & 0xffff0000u); }

// ---------- CSR build: partition -> per-shard LDS counting sort ----------

__global__ void __launch_bounds__(256)
k_part(const int* __restrict__ src, const int* __restrict__ dst,
       int* __restrict__ shcnt, int2* __restrict__ stage) {
    __shared__ int lcnt[NSH];
    __shared__ int gbase[NSH];
    int t = threadIdx.x;
    for (int i = t; i < NSH; i += 256) lcnt[i] = 0;
    __syncthreads();
    int e0 = blockIdx.x * CHUNK;
    int n = N_EDGES - e0; if (n > CHUNK) n = CHUNK; if (n < 0) n = 0;
    int2 ev[EPT]; int rk[EPT]; int sh[EPT];
    #pragma unroll
    for (int j = 0; j < EPT; ++j) {
        int i = t + j * 256;
        if (i < n) {
            int sv = __builtin_nontemporal_load(&src[e0 + i]);
            int dv = __builtin_nontemporal_load(&dst[e0 + i]);
            int k = dv / SHN;
            ev[j] = make_int2(sv, dv);
            sh[j] = k;
            rk[j] = atomicAdd(&lcnt[k], 1);
        }
    }
    __syncthreads();
    for (int i = t; i < NSH; i += 256)
        gbase[i] = atomicAdd(&shcnt[i], lcnt[i]);
    __syncthreads();
    #pragma unroll
    for (int j = 0; j < EPT; ++j) {
        int i = t + j * 256;
        if (i < n) {
            int p = gbase[sh[j]] + rk[j];
            if (p < SCAP) stage[(size_t)sh[j] * SCAP + p] = ev[j];
        }
    }
}

// also emits deg[v] and a 64-bucket global degree histogram (for pull scheduling)
__global__ void __launch_bounds__(1024)
k_build(const int2* __restrict__ stage, const int* __restrict__ shcnt,
        int* __restrict__ rowptr, float* __restrict__ dis, int* __restrict__ col,
        int* __restrict__ deg, int* __restrict__ gbins) {
    __shared__ int shc[NSH];
    __shared__ int hist[1024];
    __shared__ int A[1024];
    __shared__ int B[1024];
    __shared__ int dbin[64];
    int t = threadIdx.x;
    int s = blockIdx.x;
    if (t < NSH) shc[t] = shcnt[t];
    hist[t] = 0;
    if (t < 64) dbin[t] = 0;
    __syncthreads();
    int sb = 0;
    for (int q = 0; q < s; ++q) sb += shc[q];
    int n = shc[s]; if (n > SCAP) n = SCAP;
    const int2* st = stage + (size_t)s * SCAP;
    int v0 = s * SHN;
    for (int p = t; p < n; p += 1024)
        atomicAdd(&hist[st[p].y - v0], 1);
    __syncthreads();
    A[t] = hist[t];
    __syncthreads();
    int* cur = A; int* nxt = B;
    for (int ofs = 1; ofs < 1024; ofs <<= 1) {
        nxt[t] = cur[t] + (t >= ofs ? cur[t - ofs] : 0);
        __syncthreads();
        int* tmp = cur; cur = nxt; nxt = tmp;
    }
    int v = v0 + t;
    bool valid = (t < SHN && v < N_NODES);
    if (valid) {
        rowptr[v] = sb + cur[t] - hist[t];
        dis[v] = rsqrtf((float)(hist[t] + 1));
        deg[v] = hist[t];
        atomicAdd(&dbin[hist[t] < 63 ? hist[t] : 63], 1);
    }
    if (s == NSH - 1 && t == 0) rowptr[N_NODES] = N_EDGES;
    nxt[t] = sb + cur[t] - hist[t];
    __syncthreads();
    if (t < 64 && dbin[t]) atomicAdd(&gbins[t], dbin[t]);
    for (int p = t; p < n; p += 1024) {
        int2 ed = st[p];
        int slot = atomicAdd(&nxt[ed.y - v0], 1);
        col[slot] = ed.x;
    }
}

// exclusive scan of 64 degree bins -> bucket cursors
__global__ void k_dscan(const int* __restrict__ gbins, int* __restrict__ cursor) {
    __shared__ int a[64];
    int t = threadIdx.x;
    a[t] = gbins[t];
    __syncthreads();
    if (t == 0) { int run = 0; for (int i = 0; i < 64; ++i) { int c = a[i]; a[i] = run; run += c; } }
    __syncthreads();
    cursor[t] = a[t];
}

// scatter nodes into degree-sorted perm (LDS-aggregated bucket reservations)
__global__ void __launch_bounds__(256)
k_dperm(const int* __restrict__ deg, int* __restrict__ cursor, int* __restrict__ perm) {
    __shared__ int lb[64];
    __shared__ int base[64];
    int t = threadIdx.x;
    if (t < 64) lb[t] = 0;
    __syncthreads();
    int bin[4], rk[4];
    #pragma unroll
    for (int j = 0; j < 4; ++j) {
        int v = blockIdx.x * 1024 + j * 256 + t;
        if (v < N_NODES) {
            int d = deg[v]; bin[j] = d < 63 ? d : 63;
            rk[j] = atomicAdd(&lb[bin[j]], 1);
        } else bin[j] = -1;
    }
    __syncthreads();
    if (t < 64) base[t] = atomicAdd(&cursor[t], lb[t]);
    __syncthreads();
    #pragma unroll
    for (int j = 0; j < 4; ++j)
        if (bin[j] >= 0) perm[base[bin[j]] + rk[j]] = blockIdx.x * 1024 + j * 256 + t;
}

// ---------- persistent MFMA dense: out(bf16 Nx64) = op(A(NxK) @ W(f32 Kx64)) ----------

template<int K, bool BIAS, bool DIS, bool F32A>
__global__ void __launch_bounds__(256)
k_mfma(const void* __restrict__ Aptr, const float* __restrict__ W,
       const float* __restrict__ bias, const float* __restrict__ dis,
       u16* __restrict__ out) {
    constexpr int KB = K / 32;
    int t = threadIdx.x, wid = t >> 6, l = t & 63;
    int lr = l & 15, kc = l >> 4;
    short8v bfrag[4][KB];
    #pragma unroll
    for (int ct = 0; ct < 4; ++ct)
        #pragma unroll
        for (int kb = 0; kb < KB; ++kb)
            #pragma unroll
            for (int j = 0; j < 8; ++j)
                bfrag[ct][kb][j] = (short)f2b(W[(kb * 32 + kc * 8 + j) * HDIM + ct * 16 + lr]);
    float bb[4];
    #pragma unroll
    for (int ct = 0; ct < 4; ++ct) bb[ct] = BIAS ? bias[ct * 16 + lr] : 0.f;
    int gw = blockIdx.x * 4 + wid;
    const int nw = MFB * 4;
    for (int tile = gw; tile < NTILE; tile += nw) {
        int r0 = tile * 16;
        short8v a[KB];
        if (F32A) {
            const float* arow = (const float*)Aptr + (size_t)(r0 + lr) * K + kc * 8;
            #pragma unroll
            for (int kb = 0; kb < KB; ++kb) {
                float4 f0 = *(const float4*)(arow + kb * 32);
                float4 f1 = *(const float4*)(arow + kb * 32 + 4);
                a[kb][0] = (short)f2b(f0.x); a[kb][1] = (short)f2b(f0.y);
                a[kb][2] = (short)f2b(f0.z); a[kb][3] = (short)f2b(f0.w);
                a[kb][4] = (short)f2b(f1.x); a[kb][5] = (short)f2b(f1.y);
                a[kb][6] = (short)f2b(f1.z); a[kb][7] = (short)f2b(f1.w);
            }
        } else {
            const u16* arow = (const u16*)Aptr + (size_t)(r0 + lr) * K + kc * 8;
            #pragma unroll
            for (int kb = 0; kb < KB; ++kb)
                a[kb] = *(const short8v*)(arow + kb * 32);
        }
        f32x4 acc[4];
        #pragma unroll
        for (int ct = 0; ct < 4; ++ct) acc[ct] = (f32x4){0.f, 0.f, 0.f, 0.f};
        #pragma unroll
        for (int ct = 0; ct < 4; ++ct)
            #pragma unroll
            for (int kb = 0; kb < KB; ++kb)
                acc[ct] = __builtin_amdgcn_mfma_f32_16x16x32_bf16(a[kb], bfrag[ct][kb], acc[ct], 0, 0, 0);
        float dv[4];
        #pragma unroll
        for (int j = 0; j < 4; ++j)
            dv[j] = DIS ? dis[r0 + kc * 4 + j] : 1.f;
        #pragma unroll
        for (int ct = 0; ct < 4; ++ct)
            #pragma unroll
            for (int j = 0; j < 4; ++j) {
                int row = r0 + kc * 4 + j;
                float val = acc[ct][j];
                if (BIAS) val += bb[ct];
                if (DIS)  val *= dv[j];
                out[(size_t)row * HDIM + ct * 16 + lr] = f2b(val);
            }
    }
}

// ---------- pull v4: degree-sorted nodes, 8 nodes/wave, 4-deep pipeline ----------

template<bool MEAN>
__global__ void __launch_bounds__(256)
k_pull(const u16* __restrict__ hw, const int* __restrict__ rowptr,
       const int* __restrict__ col, const float* __restrict__ dis,
       const float* __restrict__ b, const int* __restrict__ perm,
       u16* __restrict__ hout, float* __restrict__ partial) {
    __shared__ float ms[64];
    int t = threadIdx.x, wid = t >> 6, lane = t & 63;
    int g = lane >> 3, sub = lane & 7;
    if (MEAN) { if (t < 64) ms[t] = 0.f; __syncthreads(); }
    int v = perm[blockIdx.x * 32 + wid * 8 + g];   // degree-sorted schedule
    const u16* hws = hw + sub * 8;
    uint4 sv = *(const uint4*)(hws + (size_t)v * HDIM);
    float acc[8];
    acc[0] = blo(sv.x); acc[1] = bhi(sv.x);
    acc[2] = blo(sv.y); acc[3] = bhi(sv.y);
    acc[4] = blo(sv.z); acc[5] = bhi(sv.z);
    acc[6] = blo(sv.w); acc[7] = bhi(sv.w);
    int s0 = rowptr[v], s1 = rowptr[v + 1];
    int i = s0;
    for (; i + 4 <= s1; i += 4) {
        int c0 = col[i], c1 = col[i + 1], c2 = col[i + 2], c3 = col[i + 3];
        uint4 a0 = *(const uint4*)(hws + (size_t)c0 * HDIM);
        uint4 a1 = *(const uint4*)(hws + (size_t)c1 * HDIM);
        uint4 a2 = *(const uint4*)(hws + (size_t)c2 * HDIM);
        uint4 a3 = *(const uint4*)(hws + (size_t)c3 * HDIM);
        acc[0] += blo(a0.x) + blo(a1.x); acc[1] += bhi(a0.x) + bhi(a1.x);
        acc[2] += blo(a0.y) + blo(a1.y); acc[3] += bhi(a0.y) + bhi(a1.y);
        acc[4] += blo(a0.z) + blo(a1.z); acc[5] += bhi(a0.z) + bhi(a1.z);
        acc[6] += blo(a0.w) + blo(a1.w); acc[7] += bhi(a0.w) + bhi(a1.w);
        acc[0] += blo(a2.x) + blo(a3.x); acc[1] += bhi(a2.x) + bhi(a3.x);
        acc[2] += blo(a2.y) + blo(a3.y); acc[3] += bhi(a2.y) + bhi(a3.y);
        acc[4] += blo(a2.z) + blo(a3.z); acc[5] += bhi(a2.z) + bhi(a3.z);
        acc[6] += blo(a2.w) + blo(a3.w); acc[7] += bhi(a2.w) + bhi(a3.w);
    }
    for (; i < s1; ++i) {
        int c0 = col[i];
        uint4 a0 = *(const uint4*)(hws + (size_t)c0 * HDIM);
        acc[0] += blo(a0.x); acc[1] += bhi(a0.x);
        acc[2] += blo(a0.y); acc[3] += bhi(a0.y);
        acc[4] += blo(a0.z); acc[5] += bhi(a0.z);
        acc[6] += blo(a0.w); acc[7] += bhi(a0.w);
    }
    float4 b0 = *(const float4*)&b[sub * 8];
    float4 b1 = *(const float4*)&b[sub * 8 + 4];
    float bb[8] = {b0.x, b0.y, b0.z, b0.w, b1.x, b1.y, b1.z, b1.w};
    float dv = dis[v];
    float o[8];
    u32 r[8];
    #pragma unroll
    for (int k = 0; k < 8; ++k) {
        o[k] = fmaxf(bb[k] + dv * acc[k], 0.f);
        u32 u = __float_as_uint(o[k]);
        r[k] = (u + 0x7fffu + ((u >> 16) & 1u)) >> 16;
    }
    uint4 pk;
    pk.x = r[0] | (r[1] << 16); pk.y = r[2] | (r[3] << 16);
    pk.z = r[4] | (r[5] << 16); pk.w = r[6] | (r[7] << 16);
    *(uint4*)(hout + (size_t)v * HDIM + sub * 8) = pk;
    if (MEAN) {
        #pragma unroll
        for (int k = 0; k < 8; ++k) {   // reduce across the 8 node-groups
            o[k] += __shfl_xor(o[k], 8);
            o[k] += __shfl_xor(o[k], 16);
            o[k] += __shfl_xor(o[k], 32);
        }
        if (g == 0)
            #pragma unroll
            for (int k = 0; k < 8; ++k) atomicAdd(&ms[sub * 8 + k], o[k]);
        __syncthreads();
        if (t < 64) partial[(size_t)blockIdx.x * 64 + t] = ms[t];
    }
}

// ---------- readout ----------

// parallel reduce partial[3125][64] -> partial2[64][64] (coalesced rows)
__global__ void __launch_bounds__(256)
k_red(const float* __restrict__ partial, float* __restrict__ partial2) {
    __shared__ float lds[256];
    int t = threadIdx.x, f = t & 63, g = t >> 6;
    int r0 = blockIdx.x * RROWS;
    int r1 = r0 + RROWS; if (r1 > NPB) r1 = NPB;
    float acc = 0.f;
    for (int r = r0 + g; r < r1; r += 4)
        acc += partial[(size_t)r * 64 + f];
    lds[t] = acc;
    __syncthreads();
    if (t < 64)
        partial2[(size_t)blockIdx.x * 64 + t] = lds[t] + lds[t + 64] + lds[t + 128] + lds[t + 192];
}

__global__ void __launch_bounds__(256)
k_final(const float* __restrict__ partial2,
        const float* __restrict__ gfeat,
        const float* __restrict__ wg, const float* __restrict__ bg,
        const float* __restrict__ w1, const float* __restrict__ b1,
        const float* __restrict__ w2, const float* __restrict__ b2,
        float* __restrict__ out) {
    __shared__ float red[4][HDIM];
    __shared__ float xc[2 * HDIM];
    __shared__ float hid[HDIM];
    int t = threadIdx.x, g = t >> 6, lane = t & 63;
    float s = 0.f;
    for (int p = g; p < RB; p += 4) s += partial2[(size_t)p * 64 + lane];
    red[g][lane] = s;
    __syncthreads();
    if (g == 0) {
        xc[lane] = (red[0][lane] + red[1][lane] + red[2][lane] + red[3][lane])
                   / (float)N_NODES;
    } else if (g == 1) {
        float gacc = bg[lane];
        for (int k = 0; k < F_GLOB; ++k) gacc += gfeat[k] * wg[k * HDIM + lane];
        xc[HDIM + lane] = fmaxf(gacc, 0.f);
    }
    __syncthreads();
    float hacc = 0.f;
    for (int k = g * 32; k < (g + 1) * 32; ++k) hacc += xc[k] * w1[k * HDIM + lane];
    red[g][lane] = hacc;
    __syncthreads();
    if (g == 0)
        hid[lane] = fmaxf(b1[lane] + red[0][lane] + red[1][lane]
                          + red[2][lane] + red[3][lane], 0.f);
    __syncthreads();
    float oacc = 0.f;
    for (int k = g * 16; k < (g + 1) * 16; ++k) oacc += hid[k] * w2[k * OUTDIM + lane];
    red[g][lane] = oacc;
    __syncthreads();
    if (g == 0)
        out[lane] = b2[lane] + red[0][lane] + red[1][lane]
                  + red[2][lane] + red[3][lane];
}

// ---------- launch ----------

extern "C" void kernel_launch(void* const* d_in, const int* in_sizes, int n_in,
                              void* d_out, int out_size, void* d_ws, size_t ws_size,
                              hipStream_t stream) {
    const float* x      = (const float*)d_in[0];
    const int*   eidx   = (const int*)d_in[1];
    const float* gfeat  = (const float*)d_in[2];
    const float* w_node = (const float*)d_in[3];
    const float* b_node = (const float*)d_in[4];
    const float* w_glob = (const float*)d_in[5];
    const float* b_glob = (const float*)d_in[6];
    const float* w_c[3] = {(const float*)d_in[7], (const float*)d_in[9], (const float*)d_in[11]};
    const float* b_c[3] = {(const float*)d_in[8], (const float*)d_in[10], (const float*)d_in[12]};
    const float* w_fc1  = (const float*)d_in[13];
    const float* b_fc1  = (const float*)d_in[14];
    const float* w_fc2  = (const float*)d_in[15];
    const float* b_fc2  = (const float*)d_in[16];
    float* out = (float*)d_out;

    const int* srcp = eidx;
    const int* dstp = eidx + N_EDGES;

    char* ws = (char*)d_ws;
    size_t off = 0;
    auto alloc = [&](size_t bytes) -> void* {
        void* p = ws + off;
        off = (off + bytes + 255) & ~(size_t)255;
        return p;
    };
    int*   rowptr  = (int*)  alloc((size_t)(N_NODES + 1) * 4);
    int*   shcnt   = (int*)  alloc(NSH * 4);
    int*   gbins   = (int*)  alloc(64 * 4);
    int*   cursor  = (int*)  alloc(64 * 4);
    float* dis     = (float*)alloc((size_t)N_NODES * 4);
    int*   deg     = (int*)  alloc((size_t)N_NODES * 4);
    int*   perm    = (int*)  alloc((size_t)N_NODES * 4);
    int*   col     = (int*)  alloc((size_t)N_EDGES * 4);
    int2*  stage   = (int2*) alloc((size_t)NSH * SCAP * 8);
    u16*   hbuf    = (u16*)  alloc((size_t)N_NODES * HDIM * 2);
    u16*   hwbuf   = (u16*)  alloc((size_t)N_NODES * HDIM * 2);
    float* partial = (float*)alloc((size_t)NPB * 64 * 4);
    float* partial2= (float*)alloc((size_t)RB * 64 * 4);

    hipMemsetAsync(shcnt, 0, NSH * 4, stream);
    hipMemsetAsync(gbins, 0, 64 * 4, stream);

    k_part <<<PBLK, 256, 0, stream>>>(srcp, dstp, shcnt, stage);
    k_build<<<NSH, 1024, 0, stream>>>(stage, shcnt, rowptr, dis, col, deg, gbins);
    k_dscan<<<1, 64, 0, stream>>>(gbins, cursor);
    k_dperm<<<98, 256, 0, stream>>>(deg, cursor, perm);

    // e = x @ wn + bn (f32 A, converted inline)
    k_mfma<32, true, false, true><<<MFB, 256, 0, stream>>>(x, w_node, b_node, nullptr, hbuf);
    // hw = dis * (e @ wc0)
    k_mfma<64, false, true, false><<<MFB, 256, 0, stream>>>(hbuf, w_c[0], nullptr, dis, hwbuf);
    k_pull<false><<<NPB, 256, 0, stream>>>(hwbuf, rowptr, col, dis, b_c[0], perm, hbuf, nullptr);
    k_mfma<64, false, true, false><<<MFB, 256, 0, stream>>>(hbuf, w_c[1], nullptr, dis, hwbuf);
    k_pull<false><<<NPB, 256, 0, stream>>>(hwbuf, rowptr, col, dis, b_c[1], perm, hbuf, nullptr);
    k_mfma<64, false, true, false><<<MFB, 256, 0, stream>>>(hbuf, w_c[2], nullptr, dis, hwbuf);
    k_pull<true><<<NPB, 256, 0, stream>>>(hwbuf, rowptr, col, dis, b_c[2], perm, hbuf, partial);

    k_red  <<<RB, 256, 0, stream>>>(partial, partial2);
    k_final<<<1, 256, 0, stream>>>(partial2, gfeat, w_glob, b_glob,
                                   w_fc1, b_fc1, w_fc2, b_fc2, out);
}